// Round 5
// baseline (381.694 us; speedup 1.0000x reference)
//
#include <hip/hip_runtime.h>
#include <hip/hip_bf16.h>
#include <stdint.h>

// Problem constants
#define B_ 2
#define T_ 2048
#define D_ 2048
#define H_ 32
#define HKV_ 8
#define HD_ 64
#define SCALE_ 0.125f  // HD^-0.5

typedef float floatx4 __attribute__((ext_vector_type(4)));
typedef __bf16 bf16x8 __attribute__((ext_vector_type(8)));
typedef __bf16 bf16x4 __attribute__((ext_vector_type(4)));
typedef short short4v __attribute__((ext_vector_type(4)));

__device__ inline floatx4 mfma16(bf16x8 a, bf16x8 b, floatx4 c) {
  return __builtin_amdgcn_mfma_f32_16x16x32_bf16(a, b, c, 0, 0, 0);
}

__device__ inline floatx4 mfma16k16(bf16x4 a, bf16x4 b, floatx4 c) {
#if __has_builtin(__builtin_amdgcn_mfma_f32_16x16x16_bf16)
  return __builtin_amdgcn_mfma_f32_16x16x16_bf16(a, b, c, 0, 0, 0);
#else
  return __builtin_amdgcn_mfma_f32_16x16x16bf16_1k(
      __builtin_bit_cast(short4v, a), __builtin_bit_cast(short4v, b), c, 0, 0, 0);
#endif
}

// RNE float -> bf16 bits
__device__ inline uint16_t f2bf(float f) {
  union { float f; uint32_t u; } x; x.f = f;
  uint32_t r = x.u + 0x7fffu + ((x.u >> 16) & 1u);
  return (uint16_t)(r >> 16);
}

__device__ inline uint32_t f2bf_pk(float a, float b) {
#if __has_builtin(__builtin_amdgcn_cvt_pk_bf16_f32)
  auto pk = __builtin_amdgcn_cvt_pk_bf16_f32(a, b);
  return __builtin_bit_cast(uint32_t, pk);
#else
  return (uint32_t)f2bf(a) | ((uint32_t)f2bf(b) << 16);
#endif
}

// cheap pack for P (values in [0,1]): RNE if HW op exists, else v_perm trunc.
__device__ inline uint32_t pack_p(float a, float b) {
#if __has_builtin(__builtin_amdgcn_cvt_pk_bf16_f32)
  auto pk = __builtin_amdgcn_cvt_pk_bf16_f32(a, b);
  return __builtin_bit_cast(uint32_t, pk);
#else
  return __builtin_amdgcn_perm(__builtin_bit_cast(uint32_t, b),
                               __builtin_bit_cast(uint32_t, a), 0x07060302u);
#endif
}

__device__ inline float fast_exp2(float x) {
#if __has_builtin(__builtin_amdgcn_exp2f)
  return __builtin_amdgcn_exp2f(x);
#else
  return __expf(x * 0.69314718056f);
#endif
}

#if __has_builtin(__builtin_amdgcn_global_load_lds)
#define HAVE_ASYNC_LDS 1
typedef const __attribute__((address_space(1))) uint32_t* gas1_u32;
typedef __attribute__((address_space(3))) uint32_t* las3_u32;
__device__ inline void g2lds16(const uint16_t* g, uint16_t* l) {
  __builtin_amdgcn_global_load_lds((gas1_u32)(const void*)g, (las3_u32)(void*)l, 16, 0, 0);
}
#endif

// ---------------- merged fp32 -> bf16 convert (4 elems/thread) ------------
__global__ __launch_bounds__(256) void cvt_all(
    const float* __restrict__ x, const float* __restrict__ wq,
    const float* __restrict__ wk, const float* __restrict__ wv,
    const float* __restrict__ wo,
    uint16_t* __restrict__ xb, uint16_t* __restrict__ wqb,
    uint16_t* __restrict__ wkb, uint16_t* __restrict__ wvb,
    uint16_t* __restrict__ wob) {
  int i = blockIdx.x * 256 + threadIdx.x;
  const float* src; uint16_t* dst; int off;
  if (i < 2097152)      { src = x;  dst = xb;  off = i; }
  else if (i < 3145728) { src = wq; dst = wqb; off = i - 2097152; }
  else if (i < 3407872) { src = wk; dst = wkb; off = i - 3145728; }
  else if (i < 3670016) { src = wv; dst = wvb; off = i - 3407872; }
  else                  { src = wo; dst = wob; off = i - 3670016; }
  float4 v = ((const float4*)src)[off];
  uint64_t packed = (uint64_t)f2bf_pk(v.x, v.y) | ((uint64_t)f2bf_pk(v.z, v.w) << 32);
  ((uint64_t*)dst)[off] = packed;
}

// ---------------- GEMM common: A via LDS, B direct from global ------------
// 128x128 tile, 256 threads (4 waves), double-buffered BK=32.
// LDS-BW analysis (R4): staging A+B and reading both from LDS was ~48 KB of
// LDS traffic per block-iter (~375 cyc) vs 80 cyc of MFMA -> LDS-bound at
// ~23% MfmaUtil. Fix: B fragments are read DIRECTLY from global (each
// dwordx4 covers 16 full 64B lines of the L2-resident weight panel) with a
// one-iteration register double-buffer (bnx->bfr); only A is staged in LDS.
// LDS traffic halves (stage 8 KB + read 16 KB per block-iter) and the
// barrier drain tracks 2 staging loads instead of 4. Numerics identical.
#define BM 128
#define BN 128

// frag read: logical col-group = quad (K=32 covered by one bf16x8)
__device__ inline bf16x8 frag32(const uint16_t* lds, int row, int quad) {
  int pcg = quad ^ ((row >> 1) & 3);
  return *(const bf16x8*)&lds[row * 32 + pcg * 8];
}

// A staging: slot s = c*256 + tid (c in {0,1}), 8 elems.
// row = s>>2 (=c*64 + tid>>2), pcg = tid&3, logical cg = (tid&3)^((tid>>3)&3).
#define GEMM_PROLOGUE()                                                    \
  const int srow = tid >> 2;                                               \
  const int scg = (tid & 3) ^ ((tid >> 3) & 3);                            \
  const uint16_t* gA0 = Abase + (size_t)srow * D_ + scg * 8;               \
  const uint16_t* gA1 = gA0 + (size_t)64 * D_;                             \
  const uint16_t* gBF = Bbase + (size_t)(wn + r16) * D_ + quad * 8;        \
  uint16_t* lA[2] = {As + tid * 8, As + 4096 + tid * 8};

#ifdef HAVE_ASYNC_LDS
#define GEMM_STAGE(buf, k)                                                 \
  { g2lds16(gA0 + (k), lA[buf]); g2lds16(gA1 + (k), lA[buf] + 2048); }
#else
#define GEMM_STAGE(buf, k)                                                 \
  { *(uint4*)lA[buf] = *(const uint4*)(gA0 + (k));                         \
    *(uint4*)(lA[buf] + 2048) = *(const uint4*)(gA1 + (k)); }
#endif

#define GEMM_KLOOP()                                                       \
  GEMM_PROLOGUE()                                                          \
  GEMM_STAGE(0, 0)                                                         \
  bf16x8 bfr[4], bnx[4];                                                   \
  _Pragma("unroll")                                                        \
  for (int j = 0; j < 4; j++)                                              \
    bnx[j] = *(const bf16x8*)(gBF + (size_t)(j * 16) * D_);                \
  int cur = 0;                                                             \
  for (int k0 = 0; k0 < D_; k0 += 32) {                                    \
    __syncthreads();                                                       \
    if (k0 + 32 < D_) { GEMM_STAGE(cur ^ 1, k0 + 32) }                     \
    _Pragma("unroll")                                                      \
    for (int j = 0; j < 4; j++) bfr[j] = bnx[j];                           \
    if (k0 + 32 < D_) {                                                    \
      _Pragma("unroll")                                                    \
      for (int j = 0; j < 4; j++)                                          \
        bnx[j] = *(const bf16x8*)(gBF + (size_t)(j * 16) * D_ + k0 + 32);  \
    }                                                                      \
    const uint16_t* Ac = As + cur * 4096;                                  \
    bf16x8 af[4];                                                          \
    _Pragma("unroll")                                                      \
    for (int i = 0; i < 4; i++) af[i] = frag32(Ac, wm + i * 16 + r16, quad); \
    _Pragma("unroll")                                                      \
    for (int i = 0; i < 4; i++)                                            \
      _Pragma("unroll")                                                    \
      for (int j = 0; j < 4; j++)                                          \
        acc[i][j] = mfma16(af[i], bfr[j], acc[i][j]);                      \
    cur ^= 1;                                                              \
  }

// ---------------- fused QKV projection + RMSNorm + RoPE -------------------
// Default block mapping: round-robin keeps each XCD on 3 B-panels (n === xcd
// mod 8) -> B L2-resident, A streamed. Measured best (R2 A/B).
__global__ __launch_bounds__(256) void qkv_gemm(
    const uint16_t* __restrict__ Xb, const uint16_t* __restrict__ Wqb,
    const uint16_t* __restrict__ Wkb, const uint16_t* __restrict__ Wvb,
    const float* __restrict__ qnw, const float* __restrict__ knw,
    uint16_t* __restrict__ qbf, uint16_t* __restrict__ kbf,
    uint16_t* __restrict__ vt) {
  __shared__ __align__(16) uint16_t As[2 * BM * 32];
  const int tid = threadIdx.x;
  const int m0 = blockIdx.y * BM;
  const int n0 = blockIdx.x * BN;

  const uint16_t* Wsrc; int nbase;
  if (n0 < 2048)      { Wsrc = Wqb; nbase = 0; }
  else if (n0 < 2560) { Wsrc = Wkb; nbase = 2048; }
  else                { Wsrc = Wvb; nbase = 2560; }

  const int lane = tid & 63, wave = tid >> 6;
  const int wm = (wave >> 1) * 64, wn = (wave & 1) * 64;
  const int quad = lane >> 4, r16 = lane & 15;
  const uint16_t* Abase = Xb + (size_t)m0 * D_;
  const uint16_t* Bbase = Wsrc + (size_t)(n0 - nbase) * D_;

  floatx4 acc[4][4];
  #pragma unroll
  for (int i = 0; i < 4; i++)
    #pragma unroll
    for (int j = 0; j < 4; j++) acc[i][j] = (floatx4){0.f, 0.f, 0.f, 0.f};

  GEMM_KLOOP()

  if (n0 < 2560) {
    const int isK = (n0 >= 2048);
    const float* nw = isK ? knw : qnw;
    const int head = (n0 - (isK ? 2048 : 0) + wn) >> 6;
    uint16_t* dst = isK ? kbf : qbf;
    const int NH = isK ? HKV_ : H_;
    float wreg[4];
    #pragma unroll
    for (int j = 0; j < 4; j++) wreg[j] = nw[j * 16 + r16];
    float freq[4];
    #pragma unroll
    for (int j = 0; j < 4; j++)
      freq[j] = exp2f((float)(j * 8 + (r16 >> 1)) * -0.0495300781f);  // 3^(-2p/64)
    #pragma unroll
    for (int i = 0; i < 4; i++) {
      #pragma unroll
      for (int r = 0; r < 4; r++) {
        float ss = 0.f;
        #pragma unroll
        for (int j = 0; j < 4; j++) ss += acc[i][j][r] * acc[i][j][r];
        #pragma unroll
        for (int off = 8; off; off >>= 1) ss += __shfl_xor(ss, off);
        float inv = rsqrtf(ss * (1.0f / HD_) + 1e-6f);
        int m = m0 + wm + i * 16 + quad * 4 + r;
        int b = m >> 11, t = m & (T_ - 1);
        size_t rowbase = (((size_t)b * NH + head) * T_ + t) * HD_;
        #pragma unroll
        for (int j = 0; j < 4; j++) {
          float vn = acc[i][j][r] * inv * wreg[j];
          float other = __shfl_xor(vn, 1);
          float f = (float)t * freq[j];
          float s, c;
          __sincosf(f, &s, &c);
          float outv = (r16 & 1) ? (other * s + vn * c) : (vn * c - other * s);
          dst[rowbase + j * 16 + r16] = f2bf(outv);
        }
      }
    }
  } else {
    #pragma unroll
    for (int i = 0; i < 4; i++)
      #pragma unroll
      for (int j = 0; j < 4; j++)
        #pragma unroll
        for (int r = 0; r < 4; r++) {
          int m = m0 + wm + i * 16 + quad * 4 + r;
          int n = n0 + wn + j * 16 + r16 - 2560;
          int b = m >> 11, t = m & (T_ - 1);
          int head = n >> 6, d = n & 63;
          vt[(((size_t)b * HKV_ + head) * HD_ + d) * T_ + t] = f2bf(acc[i][j][r]);
        }
  }
}

// ---------------- O projection GEMM: out = ao @ Wo^T ----------------------
// m-row XCD swizzle: 4 A-panels/XCD resident, streams B (8 MB < A 16 MB).
__global__ __launch_bounds__(256) void oproj_gemm(
    const uint16_t* __restrict__ Ab, const uint16_t* __restrict__ Bb,
    float* __restrict__ C) {
  __shared__ __align__(16) uint16_t As[2 * BM * 32];
  const int tid = threadIdx.x;
  const int lin = (int)blockIdx.y * 16 + (int)blockIdx.x;  // 512 blocks
  const int s = (lin & 7) * 64 + (lin >> 3);               // XCD swizzle
  const int m0 = (s >> 4) * BM;
  const int n0 = (s & 15) * BN;
  const int lane = tid & 63, wave = tid >> 6;
  const int wm = (wave >> 1) * 64, wn = (wave & 1) * 64;
  const int quad = lane >> 4, r16 = lane & 15;
  const uint16_t* Abase = Ab + (size_t)m0 * D_;
  const uint16_t* Bbase = Bb + (size_t)n0 * D_;

  floatx4 acc[4][4];
  #pragma unroll
  for (int i = 0; i < 4; i++)
    #pragma unroll
    for (int j = 0; j < 4; j++) acc[i][j] = (floatx4){0.f, 0.f, 0.f, 0.f};

  GEMM_KLOOP()

  #pragma unroll
  for (int i = 0; i < 4; i++)
    #pragma unroll
    for (int j = 0; j < 4; j++)
      #pragma unroll
      for (int r = 0; r < 4; r++) {
        int m = m0 + wm + i * 16 + quad * 4 + r;
        int n = n0 + wn + j * 16 + r16;
        C[(size_t)m * D_ + n] = acc[i][j][r];
      }
}

// ---------------- Flash attention: S^T + double-buffered staging ----------
// XCD swizzle groups the 16 qt-blocks of each (b,h) on one XCD ->
// that head's K/V (512 KB) stays L2-resident.
// setprio(1) wraps MFMA clusters (T5: attn-positive per m191).
#define LOG2E 1.44269504089f

__global__ __launch_bounds__(256) void attn(const uint16_t* __restrict__ qb,
                                            const uint16_t* __restrict__ kb,
                                            const uint16_t* __restrict__ vtb,
                                            uint16_t* __restrict__ ao) {
  const int tid = threadIdx.x;
  const int wave = tid >> 6, lane = tid & 63;
  const int quad = lane >> 4, r16 = lane & 15;
  const int lin = ((int)blockIdx.z * 32 + (int)blockIdx.y) * 16 + (int)blockIdx.x;
  const int s = (lin & 7) * 128 + (lin >> 3);  // XCD swizzle (1024 blocks)
  const int bx = s & 15;
  const int h  = (s >> 4) & 31;
  const int b  = s >> 9;
  const int kvh = h >> 2;

  const uint16_t* Q  = qb  + ((size_t)b * H_ + h) * T_ * HD_;
  const uint16_t* K  = kb  + ((size_t)b * HKV_ + kvh) * T_ * HD_;
  const uint16_t* Vt = vtb + ((size_t)b * HKV_ + kvh) * (size_t)HD_ * T_;

  __shared__ __align__(16) uint16_t Kl[2][64 * 64];
  __shared__ __align__(16) uint16_t Vl[2][64 * 64];

  // staging constants (K: pcg=cg^(row&7); V: pcg=cg^((row>>1)&7))
  const int l3 = lane >> 3, l7 = lane & 7, l4 = lane >> 4;
  const int cgK  = l7 ^ l3;
  const int cgV0 = l7 ^ (l4 & 7);
  const int cgV1 = l7 ^ ((4 + l4) & 7);
  const int sOff = wave * 16 * 64 + lane * 8;  // dst for row block 0; +512 for block 1

  // fragment read offsets (elements), loop-invariant
  const int koffE0 = r16 * 64 + ((quad)     ^ (r16 & 7)) * 8;
  const int koffE1 = r16 * 64 + ((4 + quad) ^ (r16 & 7)) * 8;
  int voffE[4];
  #pragma unroll
  for (int mt = 0; mt < 4; mt++)
    voffE[mt] = r16 * 64 + (((mt * 2 + (quad >> 1)) ^ ((r16 >> 1) & 7)) * 8) + (quad & 1) * 4;
  float dm[4];
  #pragma unroll
  for (int r = 0; r < 4; r++) dm[r] = (quad * 4 + r <= r16) ? 1.0f : 0.0f;

#ifdef HAVE_ASYNC_LDS
#define AT_STAGE(buf)                                                     \
  { g2lds16(kg0, &Kl[buf][sOff]); g2lds16(kg1, &Kl[buf][sOff + 512]);     \
    g2lds16(vg0, &Vl[buf][sOff]); g2lds16(vg1, &Vl[buf][sOff + 512]);     \
    kg0 += 64 * HD_; kg1 += 64 * HD_; vg0 += 64; vg1 += 64; }
#else
#define AT_STAGE(buf)                                                     \
  { *(uint4*)&Kl[buf][sOff] = *(const uint4*)kg0;                         \
    *(uint4*)&Kl[buf][sOff + 512] = *(const uint4*)kg1;                   \
    *(uint4*)&Vl[buf][sOff] = *(const uint4*)vg0;                         \
    *(uint4*)&Vl[buf][sOff + 512] = *(const uint4*)vg1;                   \
    kg0 += 64 * HD_; kg1 += 64 * HD_; vg0 += 64; vg1 += 64; }
#endif

#define AT_CHUNK(mt, MASKED)                                              \
  {                                                                       \
    bf16x8 kf0 = *(const bf16x8*)&Kc[koffE0 + (mt) * 1024];               \
    bf16x8 kf1 = *(const bf16x8*)&Kc[koffE1 + (mt) * 1024];               \
    floatx4 st = (floatx4){0.f, 0.f, 0.f, 0.f};                           \
    __builtin_amdgcn_s_setprio(1);                                        \
    st = mfma16(kf0, bq[0], st);                                          \
    st = mfma16(kf1, bq[1], st);                                          \
    __builtin_amdgcn_s_setprio(0);                                        \
    float pv[4];                                                          \
    _Pragma("unroll")                                                     \
    for (int r = 0; r < 4; r++) {                                         \
      pv[r] = fast_exp2(fmaf(st[r], SCALE_ * LOG2E, -8.0f * LOG2E));      \
      if (MASKED) pv[r] *= dm[r];                                         \
      l += pv[r];                                                         \
    }                                                                     \
    uint64_t pu = (uint64_t)pack_p(pv[0], pv[1]) |                        \
                  ((uint64_t)pack_p(pv[2], pv[3]) << 32);                 \
    bf16x4 pa = __builtin_bit_cast(bf16x4, pu);                           \
    __builtin_amdgcn_s_setprio(1);                                        \
    _Pragma("unroll")                                                     \
    for (int jn = 0; jn < 4; jn++) {                                      \
      bf16x4 vf = *(const bf16x4*)&Vc[voffE[mt] + jn * 1024];             \
      o[jn] = mfma16k16(pa, vf, o[jn]);                                   \
    }                                                                     \
    __builtin_amdgcn_s_setprio(0);                                        \
  }

  for (int pass = 0; pass < 2; pass++) {
    const int qt = pass ? bx : 31 - bx;
    const int q0 = qt * 64;
    const int Rw = q0 + wave * 16;

    bf16x8 bq[2];
    #pragma unroll
    for (int hh = 0; hh < 2; hh++)
      bq[hh] = *(const bf16x8*)(Q + (size_t)(Rw + r16) * HD_ + hh * 32 + quad * 8);

    floatx4 o[4];
    float l = 0.f;
    #pragma unroll
    for (int jn = 0; jn < 4; jn++) o[jn] = (floatx4){0.f, 0.f, 0.f, 0.f};

    const uint16_t* kg0 = K + (size_t)(wave * 16 + l3) * HD_ + cgK * 8;
    const uint16_t* kg1 = K + (size_t)(wave * 16 + 8 + l3) * HD_ + cgK * 8;
    const uint16_t* vg0 = Vt + (size_t)(wave * 16 + l3) * T_ + cgV0 * 8;
    const uint16_t* vg1 = Vt + (size_t)(wave * 16 + 8 + l3) * T_ + cgV1 * 8;

    __syncthreads();  // all readers of both buffers (prev pass) done
    AT_STAGE(0)
    int cur = 0;

    // full iterations (mask-free for every wave), prefetching it+1
    for (int it = 0; it < qt; it++) {
      __syncthreads();          // publishes buf[cur]; drains this wave's stage ops
      AT_STAGE(cur ^ 1)         // prefetch it+1 (always valid: it+1 <= qt)
      const uint16_t* Kc = Kl[cur];
      const uint16_t* Vc = Vl[cur];
      AT_CHUNK(0, false)
      AT_CHUNK(1, false)
      AT_CHUNK(2, false)
      AT_CHUNK(3, false)
      cur ^= 1;
    }
    // diagonal iteration (kt = q0)
    __syncthreads();
    {
      const uint16_t* Kc = Kl[cur];
      const uint16_t* Vc = Vl[cur];
      #pragma unroll
      for (int mt = 0; mt < 4; mt++) {
        if (mt < wave) AT_CHUNK(mt, false)
        else if (mt == wave) AT_CHUNK(mt, true)
      }
    }

    // l: reduce over quads, transpose to rows, normalize, store
    l += __shfl_xor(l, 16);
    l += __shfl_xor(l, 32);
    float lq[4];
    #pragma unroll
    for (int r = 0; r < 4; r++) lq[r] = __shfl(l, quad * 4 + r);

    #pragma unroll
    for (int jn = 0; jn < 4; jn++) {
      uint32_t u01 = f2bf_pk(o[jn][0] / lq[0], o[jn][1] / lq[1]);
      uint32_t u23 = f2bf_pk(o[jn][2] / lq[2], o[jn][3] / lq[3]);
      int t0 = Rw + quad * 4;
      size_t base = ((size_t)b * T_ + t0) * (H_ * HD_) + h * HD_ + jn * 16 + r16;
      ao[base]                = (uint16_t)u01;
      ao[base + 1 * H_ * HD_] = (uint16_t)(u01 >> 16);
      ao[base + 2 * H_ * HD_] = (uint16_t)u23;
      ao[base + 3 * H_ * HD_] = (uint16_t)(u23 >> 16);
    }
  }
#undef AT_STAGE
#undef AT_CHUNK
}

extern "C" void kernel_launch(void* const* d_in, const int* in_sizes, int n_in,
                              void* d_out, int out_size, void* d_ws, size_t ws_size,
                              hipStream_t stream) {
  const float* x  = (const float*)d_in[0];
  const float* Wq = (const float*)d_in[1];
  const float* Wk = (const float*)d_in[2];
  const float* Wv = (const float*)d_in[3];
  const float* Wo = (const float*)d_in[4];
  const float* qw = (const float*)d_in[5];
  const float* kw = (const float*)d_in[6];
  float* out = (float*)d_out;

  char* ws = (char*)d_ws;
  uint16_t* xb  = (uint16_t*)(ws);               // 16 MB  x bf16 (later: ao bf16)
  uint16_t* wqb = (uint16_t*)(ws + 16777216);    // 8 MB
  uint16_t* wkb = (uint16_t*)(ws + 25165824);    // 2 MB
  uint16_t* wvb = (uint16_t*)(ws + 27262976);    // 2 MB
  uint16_t* wob = (uint16_t*)(ws + 29360128);    // 8 MB
  uint16_t* qbf = (uint16_t*)(ws + 37748736);    // 16 MB  q bf16 (b,h,t,d) post norm+rope
  uint16_t* kbf = (uint16_t*)(ws + 54525952);    // 4 MB   k bf16 (b,kvh,t,d)
  uint16_t* vtb = (uint16_t*)(ws + 58720256);    // 4 MB   V^T bf16 (b,kvh,d,t)
  uint16_t* aob = xb;

  cvt_all<<<18432, 256, 0, stream>>>(x, Wq, Wk, Wv, Wo, xb, wqb, wkb, wvb, wob);

  qkv_gemm<<<dim3(24, 32), 256, 0, stream>>>(xb, wqb, wkb, wvb, qw, kw, qbf, kbf, vtb);

  attn<<<dim3(16, 32, 2), 256, 0, stream>>>(qbf, kbf, vtb, aob);

  oproj_gemm<<<dim3(16, 32), 256, 0, stream>>>(aob, wob, out);
}

// Round 6
// 348.410 us; speedup vs baseline: 1.0955x; 1.0955x over previous
//
#include <hip/hip_runtime.h>
#include <hip/hip_bf16.h>
#include <stdint.h>

// Problem constants
#define B_ 2
#define T_ 2048
#define D_ 2048
#define H_ 32
#define HKV_ 8
#define HD_ 64
#define SCALE_ 0.125f  // HD^-0.5

typedef float floatx4 __attribute__((ext_vector_type(4)));
typedef __bf16 bf16x8 __attribute__((ext_vector_type(8)));
typedef __bf16 bf16x4 __attribute__((ext_vector_type(4)));
typedef short short4v __attribute__((ext_vector_type(4)));

__device__ inline floatx4 mfma16(bf16x8 a, bf16x8 b, floatx4 c) {
  return __builtin_amdgcn_mfma_f32_16x16x32_bf16(a, b, c, 0, 0, 0);
}

__device__ inline floatx4 mfma16k16(bf16x4 a, bf16x4 b, floatx4 c) {
#if __has_builtin(__builtin_amdgcn_mfma_f32_16x16x16_bf16)
  return __builtin_amdgcn_mfma_f32_16x16x16_bf16(a, b, c, 0, 0, 0);
#else
  return __builtin_amdgcn_mfma_f32_16x16x16bf16_1k(
      __builtin_bit_cast(short4v, a), __builtin_bit_cast(short4v, b), c, 0, 0, 0);
#endif
}

// RNE float -> bf16 bits
__device__ inline uint16_t f2bf(float f) {
  union { float f; uint32_t u; } x; x.f = f;
  uint32_t r = x.u + 0x7fffu + ((x.u >> 16) & 1u);
  return (uint16_t)(r >> 16);
}

__device__ inline uint32_t f2bf_pk(float a, float b) {
#if __has_builtin(__builtin_amdgcn_cvt_pk_bf16_f32)
  auto pk = __builtin_amdgcn_cvt_pk_bf16_f32(a, b);
  return __builtin_bit_cast(uint32_t, pk);
#else
  return (uint32_t)f2bf(a) | ((uint32_t)f2bf(b) << 16);
#endif
}

// cheap pack for P (values in [0,1]): RNE if HW op exists, else v_perm trunc.
__device__ inline uint32_t pack_p(float a, float b) {
#if __has_builtin(__builtin_amdgcn_cvt_pk_bf16_f32)
  auto pk = __builtin_amdgcn_cvt_pk_bf16_f32(a, b);
  return __builtin_bit_cast(uint32_t, pk);
#else
  return __builtin_amdgcn_perm(__builtin_bit_cast(uint32_t, b),
                               __builtin_bit_cast(uint32_t, a), 0x07060302u);
#endif
}

__device__ inline float fast_exp2(float x) {
#if __has_builtin(__builtin_amdgcn_exp2f)
  return __builtin_amdgcn_exp2f(x);
#else
  return __expf(x * 0.69314718056f);
#endif
}

#if __has_builtin(__builtin_amdgcn_global_load_lds)
#define HAVE_ASYNC_LDS 1
typedef const __attribute__((address_space(1))) uint32_t* gas1_u32;
typedef __attribute__((address_space(3))) uint32_t* las3_u32;
__device__ inline void g2lds16(const uint16_t* g, uint16_t* l) {
  __builtin_amdgcn_global_load_lds((gas1_u32)(const void*)g, (las3_u32)(void*)l, 16, 0, 0);
}
#endif

// ---------------- merged fp32 -> bf16 convert (4 elems/thread) ------------
__global__ __launch_bounds__(256) void cvt_all(
    const float* __restrict__ x, const float* __restrict__ wq,
    const float* __restrict__ wk, const float* __restrict__ wv,
    const float* __restrict__ wo,
    uint16_t* __restrict__ xb, uint16_t* __restrict__ wqb,
    uint16_t* __restrict__ wkb, uint16_t* __restrict__ wvb,
    uint16_t* __restrict__ wob) {
  int i = blockIdx.x * 256 + threadIdx.x;
  const float* src; uint16_t* dst; int off;
  if (i < 2097152)      { src = x;  dst = xb;  off = i; }
  else if (i < 3145728) { src = wq; dst = wqb; off = i - 2097152; }
  else if (i < 3407872) { src = wk; dst = wkb; off = i - 3145728; }
  else if (i < 3670016) { src = wv; dst = wvb; off = i - 3407872; }
  else                  { src = wo; dst = wob; off = i - 3670016; }
  float4 v = ((const float4*)src)[off];
  uint64_t packed = (uint64_t)f2bf_pk(v.x, v.y) | ((uint64_t)f2bf_pk(v.z, v.w) << 32);
  ((uint64_t*)dst)[off] = packed;
}

// ---------------- GEMM common: 128x64 tile, 2-wave blocks, BK=32 ----------
// Stall model (R0-R5 evidence): iteration = stage latency (~400-900cy, A
// misses L2) + compute (~350cy); __syncthreads drains vmcnt(0) so in-flight
// window = one compute phase. Hiding needs CONCURRENT INDEPENDENT BARRIER
// GROUPS: at 3 blocks/CU (old 128x128 grid=768) only 2x350cy covers a 900cy
// stall -> MfmaUtil ~23%. This geometry: same per-wave 64x64 work/acc/VGPR,
// same sync structure, but 24 KB LDS + 2-wave blocks -> 6 blocks/CU (qkv
// grid 1536), 5x350 > 900 -> stall covered. B-reuse per byte unchanged
// (32 m-tiles either way); A re-reads double but are L2/L3-served.
#define BM 128
#define BN 64

// frag read: logical col-group = quad (K=32 covered by one bf16x8)
// phys cg = quad ^ ((row>>1)&3); byte = row*64 + pcg*16 -> conflict-free.
__device__ inline bf16x8 frag32(const uint16_t* lds, int row, int quad) {
  int pcg = quad ^ ((row >> 1) & 3);
  return *(const bf16x8*)&lds[row * 32 + pcg * 8];
}

// Staging (128 threads): slot s = chunk*128 + tid, 8 elems each.
// row = s>>2 = chunk*32 + (tid>>2); pcg = tid&3;
// logical cg = pcg ^ ((row>>1)&3) = (tid&3)^((tid>>3)&3)  (chunk*16 === 0 mod 4).
// LDS dst = buf + s*8 = row*32 + pcg*8 (matches frag32) and is wave-uniform
// base + lane*16B as global_load_lds requires.
#define GEMM_PROLOGUE()                                                    \
  const int srow = tid >> 2;                                               \
  const int scg = (tid & 3) ^ ((tid >> 3) & 3);                            \
  const uint16_t* gA0 = Abase + (size_t)srow * D_ + scg * 8;               \
  const uint16_t* gA1 = gA0 + (size_t)32 * D_;                             \
  const uint16_t* gA2 = gA0 + (size_t)64 * D_;                             \
  const uint16_t* gA3 = gA0 + (size_t)96 * D_;                             \
  const uint16_t* gB0 = Bbase + (size_t)srow * D_ + scg * 8;               \
  const uint16_t* gB1 = gB0 + (size_t)32 * D_;                             \
  uint16_t* lA[2] = {As + tid * 8, As + 4096 + tid * 8};                   \
  uint16_t* lB[2] = {Bs + tid * 8, Bs + 2048 + tid * 8};

#ifdef HAVE_ASYNC_LDS
#define GEMM_STAGE(buf, k)                                                 \
  { g2lds16(gA0 + (k), lA[buf]);        g2lds16(gA1 + (k), lA[buf] + 1024);\
    g2lds16(gA2 + (k), lA[buf] + 2048); g2lds16(gA3 + (k), lA[buf] + 3072);\
    g2lds16(gB0 + (k), lB[buf]);        g2lds16(gB1 + (k), lB[buf] + 1024); }
#else
#define GEMM_STAGE(buf, k)                                                 \
  { *(uint4*)lA[buf] = *(const uint4*)(gA0 + (k));                         \
    *(uint4*)(lA[buf] + 1024) = *(const uint4*)(gA1 + (k));                \
    *(uint4*)(lA[buf] + 2048) = *(const uint4*)(gA2 + (k));                \
    *(uint4*)(lA[buf] + 3072) = *(const uint4*)(gA3 + (k));                \
    *(uint4*)lB[buf] = *(const uint4*)(gB0 + (k));                         \
    *(uint4*)(lB[buf] + 1024) = *(const uint4*)(gB1 + (k)); }
#endif

#define GEMM_KLOOP()                                                       \
  GEMM_PROLOGUE()                                                          \
  GEMM_STAGE(0, 0)                                                         \
  int cur = 0;                                                             \
  for (int k0 = 0; k0 < D_; k0 += 32) {                                    \
    __syncthreads();                                                       \
    if (k0 + 32 < D_) { GEMM_STAGE(cur ^ 1, k0 + 32) }                     \
    const uint16_t* Ac = As + cur * 4096;                                  \
    const uint16_t* Bc = Bs + cur * 2048;                                  \
    bf16x8 af[4], bfr[4];                                                  \
    _Pragma("unroll")                                                      \
    for (int i = 0; i < 4; i++) af[i] = frag32(Ac, wm + i * 16 + r16, quad); \
    _Pragma("unroll")                                                      \
    for (int j = 0; j < 4; j++) bfr[j] = frag32(Bc, j * 16 + r16, quad);   \
    _Pragma("unroll")                                                      \
    for (int i = 0; i < 4; i++)                                            \
      _Pragma("unroll")                                                    \
      for (int j = 0; j < 4; j++)                                          \
        acc[i][j] = mfma16(af[i], bfr[j], acc[i][j]);                      \
    cur ^= 1;                                                              \
  }

// ---------------- fused QKV projection + RMSNorm + RoPE -------------------
// Grid dim3(48,32)=1536 blocks of 128 thr; default mapping keeps each XCD on
// n-tiles === xcd (mod 8) -> 6 B-panels (1.5 MB) L2-resident, A streamed.
__global__ __launch_bounds__(128) void qkv_gemm(
    const uint16_t* __restrict__ Xb, const uint16_t* __restrict__ Wqb,
    const uint16_t* __restrict__ Wkb, const uint16_t* __restrict__ Wvb,
    const float* __restrict__ qnw, const float* __restrict__ knw,
    uint16_t* __restrict__ qbf, uint16_t* __restrict__ kbf,
    uint16_t* __restrict__ vt) {
  __shared__ __align__(16) uint16_t As[2 * BM * 32];
  __shared__ __align__(16) uint16_t Bs[2 * BN * 32];
  const int tid = threadIdx.x;
  const int m0 = blockIdx.y * BM;
  const int n0 = blockIdx.x * BN;

  const uint16_t* Wsrc; int nbase;
  if (n0 < 2048)      { Wsrc = Wqb; nbase = 0; }
  else if (n0 < 2560) { Wsrc = Wkb; nbase = 2048; }
  else                { Wsrc = Wvb; nbase = 2560; }

  const int lane = tid & 63, wave = tid >> 6;
  const int wm = wave * 64;
  const int quad = lane >> 4, r16 = lane & 15;
  const uint16_t* Abase = Xb + (size_t)m0 * D_;
  const uint16_t* Bbase = Wsrc + (size_t)(n0 - nbase) * D_;

  floatx4 acc[4][4];
  #pragma unroll
  for (int i = 0; i < 4; i++)
    #pragma unroll
    for (int j = 0; j < 4; j++) acc[i][j] = (floatx4){0.f, 0.f, 0.f, 0.f};

  GEMM_KLOOP()

  if (n0 < 2560) {
    const int isK = (n0 >= 2048);
    const float* nw = isK ? knw : qnw;
    const int head = (n0 - (isK ? 2048 : 0)) >> 6;  // 64-wide tile: one head
    uint16_t* dst = isK ? kbf : qbf;
    const int NH = isK ? HKV_ : H_;
    float wreg[4];
    #pragma unroll
    for (int j = 0; j < 4; j++) wreg[j] = nw[j * 16 + r16];
    float freq[4];
    #pragma unroll
    for (int j = 0; j < 4; j++)
      freq[j] = exp2f((float)(j * 8 + (r16 >> 1)) * -0.0495300781f);  // 3^(-2p/64)
    #pragma unroll
    for (int i = 0; i < 4; i++) {
      #pragma unroll
      for (int r = 0; r < 4; r++) {
        float ss = 0.f;
        #pragma unroll
        for (int j = 0; j < 4; j++) ss += acc[i][j][r] * acc[i][j][r];
        #pragma unroll
        for (int off = 8; off; off >>= 1) ss += __shfl_xor(ss, off);
        float inv = rsqrtf(ss * (1.0f / HD_) + 1e-6f);
        int m = m0 + wm + i * 16 + quad * 4 + r;
        int b = m >> 11, t = m & (T_ - 1);
        size_t rowbase = (((size_t)b * NH + head) * T_ + t) * HD_;
        #pragma unroll
        for (int j = 0; j < 4; j++) {
          float vn = acc[i][j][r] * inv * wreg[j];
          float other = __shfl_xor(vn, 1);
          float f = (float)t * freq[j];
          float s, c;
          __sincosf(f, &s, &c);
          float outv = (r16 & 1) ? (other * s + vn * c) : (vn * c - other * s);
          dst[rowbase + j * 16 + r16] = f2bf(outv);
        }
      }
    }
  } else {
    const int head = (n0 - 2560) >> 6;
    #pragma unroll
    for (int i = 0; i < 4; i++)
      #pragma unroll
      for (int j = 0; j < 4; j++)
        #pragma unroll
        for (int r = 0; r < 4; r++) {
          int m = m0 + wm + i * 16 + quad * 4 + r;
          int d = j * 16 + r16;
          int b = m >> 11, t = m & (T_ - 1);
          vt[(((size_t)b * HKV_ + head) * HD_ + d) * T_ + t] = f2bf(acc[i][j][r]);
        }
  }
}

// ---------------- O projection GEMM: out = ao @ Wo^T ----------------------
// Grid dim3(32,32)=1024 blocks of 128 thr = 4/CU (vs 2 at 128x128).
__global__ __launch_bounds__(128) void oproj_gemm(
    const uint16_t* __restrict__ Ab, const uint16_t* __restrict__ Bb,
    float* __restrict__ C) {
  __shared__ __align__(16) uint16_t As[2 * BM * 32];
  __shared__ __align__(16) uint16_t Bs[2 * BN * 32];
  const int tid = threadIdx.x;
  const int m0 = blockIdx.y * BM;
  const int n0 = blockIdx.x * BN;
  const int lane = tid & 63, wave = tid >> 6;
  const int wm = wave * 64;
  const int quad = lane >> 4, r16 = lane & 15;
  const uint16_t* Abase = Ab + (size_t)m0 * D_;
  const uint16_t* Bbase = Bb + (size_t)n0 * D_;

  floatx4 acc[4][4];
  #pragma unroll
  for (int i = 0; i < 4; i++)
    #pragma unroll
    for (int j = 0; j < 4; j++) acc[i][j] = (floatx4){0.f, 0.f, 0.f, 0.f};

  GEMM_KLOOP()

  #pragma unroll
  for (int i = 0; i < 4; i++)
    #pragma unroll
    for (int j = 0; j < 4; j++)
      #pragma unroll
      for (int r = 0; r < 4; r++) {
        int m = m0 + wm + i * 16 + quad * 4 + r;
        int n = n0 + j * 16 + r16;
        C[(size_t)m * D_ + n] = acc[i][j][r];
      }
}

// ---------------- Flash attention: S^T + double-buffered staging ----------
// XCD swizzle groups the 16 qt-blocks of each (b,h) on one XCD ->
// that head's K/V (512 KB) stays L2-resident.
// setprio(1) wraps MFMA clusters (T5: attn-positive per m191).
#define LOG2E 1.44269504089f

__global__ __launch_bounds__(256) void attn(const uint16_t* __restrict__ qb,
                                            const uint16_t* __restrict__ kb,
                                            const uint16_t* __restrict__ vtb,
                                            uint16_t* __restrict__ ao) {
  const int tid = threadIdx.x;
  const int wave = tid >> 6, lane = tid & 63;
  const int quad = lane >> 4, r16 = lane & 15;
  const int lin = ((int)blockIdx.z * 32 + (int)blockIdx.y) * 16 + (int)blockIdx.x;
  const int s = (lin & 7) * 128 + (lin >> 3);  // XCD swizzle (1024 blocks)
  const int bx = s & 15;
  const int h  = (s >> 4) & 31;
  const int b  = s >> 9;
  const int kvh = h >> 2;

  const uint16_t* Q  = qb  + ((size_t)b * H_ + h) * T_ * HD_;
  const uint16_t* K  = kb  + ((size_t)b * HKV_ + kvh) * T_ * HD_;
  const uint16_t* Vt = vtb + ((size_t)b * HKV_ + kvh) * (size_t)HD_ * T_;

  __shared__ __align__(16) uint16_t Kl[2][64 * 64];
  __shared__ __align__(16) uint16_t Vl[2][64 * 64];

  // staging constants (K: pcg=cg^(row&7); V: pcg=cg^((row>>1)&7))
  const int l3 = lane >> 3, l7 = lane & 7, l4 = lane >> 4;
  const int cgK  = l7 ^ l3;
  const int cgV0 = l7 ^ (l4 & 7);
  const int cgV1 = l7 ^ ((4 + l4) & 7);
  const int sOff = wave * 16 * 64 + lane * 8;  // dst for row block 0; +512 for block 1

  // fragment read offsets (elements), loop-invariant
  const int koffE0 = r16 * 64 + ((quad)     ^ (r16 & 7)) * 8;
  const int koffE1 = r16 * 64 + ((4 + quad) ^ (r16 & 7)) * 8;
  int voffE[4];
  #pragma unroll
  for (int mt = 0; mt < 4; mt++)
    voffE[mt] = r16 * 64 + (((mt * 2 + (quad >> 1)) ^ ((r16 >> 1) & 7)) * 8) + (quad & 1) * 4;
  float dm[4];
  #pragma unroll
  for (int r = 0; r < 4; r++) dm[r] = (quad * 4 + r <= r16) ? 1.0f : 0.0f;

#ifdef HAVE_ASYNC_LDS
#define AT_STAGE(buf)                                                     \
  { g2lds16(kg0, &Kl[buf][sOff]); g2lds16(kg1, &Kl[buf][sOff + 512]);     \
    g2lds16(vg0, &Vl[buf][sOff]); g2lds16(vg1, &Vl[buf][sOff + 512]);     \
    kg0 += 64 * HD_; kg1 += 64 * HD_; vg0 += 64; vg1 += 64; }
#else
#define AT_STAGE(buf)                                                     \
  { *(uint4*)&Kl[buf][sOff] = *(const uint4*)kg0;                         \
    *(uint4*)&Kl[buf][sOff + 512] = *(const uint4*)kg1;                   \
    *(uint4*)&Vl[buf][sOff] = *(const uint4*)vg0;                         \
    *(uint4*)&Vl[buf][sOff + 512] = *(const uint4*)vg1;                   \
    kg0 += 64 * HD_; kg1 += 64 * HD_; vg0 += 64; vg1 += 64; }
#endif

#define AT_CHUNK(mt, MASKED)                                              \
  {                                                                       \
    bf16x8 kf0 = *(const bf16x8*)&Kc[koffE0 + (mt) * 1024];               \
    bf16x8 kf1 = *(const bf16x8*)&Kc[koffE1 + (mt) * 1024];               \
    floatx4 st = (floatx4){0.f, 0.f, 0.f, 0.f};                           \
    __builtin_amdgcn_s_setprio(1);                                        \
    st = mfma16(kf0, bq[0], st);                                          \
    st = mfma16(kf1, bq[1], st);                                          \
    __builtin_amdgcn_s_setprio(0);                                        \
    float pv[4];                                                          \
    _Pragma("unroll")                                                     \
    for (int r = 0; r < 4; r++) {                                         \
      pv[r] = fast_exp2(fmaf(st[r], SCALE_ * LOG2E, -8.0f * LOG2E));      \
      if (MASKED) pv[r] *= dm[r];                                         \
      l += pv[r];                                                         \
    }                                                                     \
    uint64_t pu = (uint64_t)pack_p(pv[0], pv[1]) |                        \
                  ((uint64_t)pack_p(pv[2], pv[3]) << 32);                 \
    bf16x4 pa = __builtin_bit_cast(bf16x4, pu);                           \
    __builtin_amdgcn_s_setprio(1);                                        \
    _Pragma("unroll")                                                     \
    for (int jn = 0; jn < 4; jn++) {                                      \
      bf16x4 vf = *(const bf16x4*)&Vc[voffE[mt] + jn * 1024];             \
      o[jn] = mfma16k16(pa, vf, o[jn]);                                   \
    }                                                                     \
    __builtin_amdgcn_s_setprio(0);                                        \
  }

  for (int pass = 0; pass < 2; pass++) {
    const int qt = pass ? bx : 31 - bx;
    const int q0 = qt * 64;
    const int Rw = q0 + wave * 16;

    bf16x8 bq[2];
    #pragma unroll
    for (int hh = 0; hh < 2; hh++)
      bq[hh] = *(const bf16x8*)(Q + (size_t)(Rw + r16) * HD_ + hh * 32 + quad * 8);

    floatx4 o[4];
    float l = 0.f;
    #pragma unroll
    for (int jn = 0; jn < 4; jn++) o[jn] = (floatx4){0.f, 0.f, 0.f, 0.f};

    const uint16_t* kg0 = K + (size_t)(wave * 16 + l3) * HD_ + cgK * 8;
    const uint16_t* kg1 = K + (size_t)(wave * 16 + 8 + l3) * HD_ + cgK * 8;
    const uint16_t* vg0 = Vt + (size_t)(wave * 16 + l3) * T_ + cgV0 * 8;
    const uint16_t* vg1 = Vt + (size_t)(wave * 16 + 8 + l3) * T_ + cgV1 * 8;

    __syncthreads();  // all readers of both buffers (prev pass) done
    AT_STAGE(0)
    int cur = 0;

    // full iterations (mask-free for every wave), prefetching it+1
    for (int it = 0; it < qt; it++) {
      __syncthreads();          // publishes buf[cur]; drains this wave's stage ops
      AT_STAGE(cur ^ 1)         // prefetch it+1 (always valid: it+1 <= qt)
      const uint16_t* Kc = Kl[cur];
      const uint16_t* Vc = Vl[cur];
      AT_CHUNK(0, false)
      AT_CHUNK(1, false)
      AT_CHUNK(2, false)
      AT_CHUNK(3, false)
      cur ^= 1;
    }
    // diagonal iteration (kt = q0)
    __syncthreads();
    {
      const uint16_t* Kc = Kl[cur];
      const uint16_t* Vc = Vl[cur];
      #pragma unroll
      for (int mt = 0; mt < 4; mt++) {
        if (mt < wave) AT_CHUNK(mt, false)
        else if (mt == wave) AT_CHUNK(mt, true)
      }
    }

    // l: reduce over quads, transpose to rows, normalize, store
    l += __shfl_xor(l, 16);
    l += __shfl_xor(l, 32);
    float lq[4];
    #pragma unroll
    for (int r = 0; r < 4; r++) lq[r] = __shfl(l, quad * 4 + r);

    #pragma unroll
    for (int jn = 0; jn < 4; jn++) {
      uint32_t u01 = f2bf_pk(o[jn][0] / lq[0], o[jn][1] / lq[1]);
      uint32_t u23 = f2bf_pk(o[jn][2] / lq[2], o[jn][3] / lq[3]);
      int t0 = Rw + quad * 4;
      size_t base = ((size_t)b * T_ + t0) * (H_ * HD_) + h * HD_ + jn * 16 + r16;
      ao[base]                = (uint16_t)u01;
      ao[base + 1 * H_ * HD_] = (uint16_t)(u01 >> 16);
      ao[base + 2 * H_ * HD_] = (uint16_t)u23;
      ao[base + 3 * H_ * HD_] = (uint16_t)(u23 >> 16);
    }
  }
#undef AT_STAGE
#undef AT_CHUNK
}

extern "C" void kernel_launch(void* const* d_in, const int* in_sizes, int n_in,
                              void* d_out, int out_size, void* d_ws, size_t ws_size,
                              hipStream_t stream) {
  const float* x  = (const float*)d_in[0];
  const float* Wq = (const float*)d_in[1];
  const float* Wk = (const float*)d_in[2];
  const float* Wv = (const float*)d_in[3];
  const float* Wo = (const float*)d_in[4];
  const float* qw = (const float*)d_in[5];
  const float* kw = (const float*)d_in[6];
  float* out = (float*)d_out;

  char* ws = (char*)d_ws;
  uint16_t* xb  = (uint16_t*)(ws);               // 16 MB  x bf16 (later: ao bf16)
  uint16_t* wqb = (uint16_t*)(ws + 16777216);    // 8 MB
  uint16_t* wkb = (uint16_t*)(ws + 25165824);    // 2 MB
  uint16_t* wvb = (uint16_t*)(ws + 27262976);    // 2 MB
  uint16_t* wob = (uint16_t*)(ws + 29360128);    // 8 MB
  uint16_t* qbf = (uint16_t*)(ws + 37748736);    // 16 MB  q bf16 (b,h,t,d) post norm+rope
  uint16_t* kbf = (uint16_t*)(ws + 54525952);    // 4 MB   k bf16 (b,kvh,t,d)
  uint16_t* vtb = (uint16_t*)(ws + 58720256);    // 4 MB   V^T bf16 (b,kvh,d,t)
  uint16_t* aob = xb;

  cvt_all<<<18432, 256, 0, stream>>>(x, Wq, Wk, Wv, Wo, xb, wqb, wkb, wvb, wob);

  qkv_gemm<<<dim3(48, 32), 128, 0, stream>>>(xb, wqb, wkb, wvb, qw, kw, qbf, kbf, vtb);

  attn<<<dim3(16, 32, 2), 256, 0, stream>>>(qbf, kbf, vtb, aob);

  oproj_gemm<<<dim3(32, 32), 128, 0, stream>>>(aob, wob, out);
}

// Round 7
// 305.820 us; speedup vs baseline: 1.2481x; 1.1393x over previous
//
#include <hip/hip_runtime.h>
#include <hip/hip_bf16.h>
#include <stdint.h>

// Problem constants
#define B_ 2
#define T_ 2048
#define D_ 2048
#define H_ 32
#define HKV_ 8
#define HD_ 64
#define SCALE_ 0.125f  // HD^-0.5

typedef float floatx4 __attribute__((ext_vector_type(4)));
typedef __bf16 bf16x8 __attribute__((ext_vector_type(8)));
typedef __bf16 bf16x4 __attribute__((ext_vector_type(4)));
typedef short short4v __attribute__((ext_vector_type(4)));

__device__ inline floatx4 mfma16(bf16x8 a, bf16x8 b, floatx4 c) {
  return __builtin_amdgcn_mfma_f32_16x16x32_bf16(a, b, c, 0, 0, 0);
}

__device__ inline floatx4 mfma16k16(bf16x4 a, bf16x4 b, floatx4 c) {
#if __has_builtin(__builtin_amdgcn_mfma_f32_16x16x16_bf16)
  return __builtin_amdgcn_mfma_f32_16x16x16_bf16(a, b, c, 0, 0, 0);
#else
  return __builtin_amdgcn_mfma_f32_16x16x16bf16_1k(
      __builtin_bit_cast(short4v, a), __builtin_bit_cast(short4v, b), c, 0, 0, 0);
#endif
}

// RNE float -> bf16 bits
__device__ inline uint16_t f2bf(float f) {
  union { float f; uint32_t u; } x; x.f = f;
  uint32_t r = x.u + 0x7fffu + ((x.u >> 16) & 1u);
  return (uint16_t)(r >> 16);
}

__device__ inline uint32_t f2bf_pk(float a, float b) {
#if __has_builtin(__builtin_amdgcn_cvt_pk_bf16_f32)
  auto pk = __builtin_amdgcn_cvt_pk_bf16_f32(a, b);
  return __builtin_bit_cast(uint32_t, pk);
#else
  return (uint32_t)f2bf(a) | ((uint32_t)f2bf(b) << 16);
#endif
}

// cheap pack for P (values in [0,1]): RNE if HW op exists, else v_perm trunc.
__device__ inline uint32_t pack_p(float a, float b) {
#if __has_builtin(__builtin_amdgcn_cvt_pk_bf16_f32)
  auto pk = __builtin_amdgcn_cvt_pk_bf16_f32(a, b);
  return __builtin_bit_cast(uint32_t, pk);
#else
  return __builtin_amdgcn_perm(__builtin_bit_cast(uint32_t, b),
                               __builtin_bit_cast(uint32_t, a), 0x07060302u);
#endif
}

__device__ inline float fast_exp2(float x) {
#if __has_builtin(__builtin_amdgcn_exp2f)
  return __builtin_amdgcn_exp2f(x);
#else
  return __expf(x * 0.69314718056f);
#endif
}

#if __has_builtin(__builtin_amdgcn_global_load_lds)
#define HAVE_ASYNC_LDS 1
typedef const __attribute__((address_space(1))) uint32_t* gas1_u32;
typedef __attribute__((address_space(3))) uint32_t* las3_u32;
__device__ inline void g2lds16(const uint16_t* g, uint16_t* l) {
  __builtin_amdgcn_global_load_lds((gas1_u32)(const void*)g, (las3_u32)(void*)l, 16, 0, 0);
}
#endif

// ---------------- merged fp32 -> bf16 convert (4 elems/thread) ------------
__global__ __launch_bounds__(256) void cvt_all(
    const float* __restrict__ x, const float* __restrict__ wq,
    const float* __restrict__ wk, const float* __restrict__ wv,
    const float* __restrict__ wo,
    uint16_t* __restrict__ xb, uint16_t* __restrict__ wqb,
    uint16_t* __restrict__ wkb, uint16_t* __restrict__ wvb,
    uint16_t* __restrict__ wob) {
  int i = blockIdx.x * 256 + threadIdx.x;
  const float* src; uint16_t* dst; int off;
  if (i < 2097152)      { src = x;  dst = xb;  off = i; }
  else if (i < 3145728) { src = wq; dst = wqb; off = i - 2097152; }
  else if (i < 3407872) { src = wk; dst = wkb; off = i - 3145728; }
  else if (i < 3670016) { src = wv; dst = wvb; off = i - 3407872; }
  else                  { src = wo; dst = wob; off = i - 3670016; }
  float4 v = ((const float4*)src)[off];
  uint64_t packed = (uint64_t)f2bf_pk(v.x, v.y) | ((uint64_t)f2bf_pk(v.z, v.w) << 32);
  ((uint64_t*)dst)[off] = packed;
}

// ---------------- GEMM common: R4 geometry + counted-vmcnt K-loop ---------
// 128x128 tile, 256 threads (4 waves), 32 KiB LDS, BK=32, double-buffered.
// T4 counted-vmcnt (the measured fix for the drain stall, m218): 2-deep
// pipeline, loads for tile t issued at iter t-2 and waited with vmcnt(4)
// (oldest-4 in-order retirement = tile t landed) -> never vmcnt(0) in the
// main loop; loads fly across ~2 compute phases (~700cy > HBM latency).
// Per iter: vmcnt(4)+bar; 8x ds_read_b128 -> regs; lgkmcnt(0)+bar (WAR
// fence); STAGE tile t+2 into just-freed buffer; 16 MFMA. All barriers are
// asm with "memory" clobber (no LDS read / stage issue crosses; MFMA is
// ordered by data dependence on the compiler-visible frag loads).
#define BM 128
#define BN 128

// frag read: logical col-group = quad (K=32 covered by one bf16x8)
__device__ inline bf16x8 frag32(const uint16_t* lds, int row, int quad) {
  int pcg = quad ^ ((row >> 1) & 3);
  return *(const bf16x8*)&lds[row * 32 + pcg * 8];
}

// Staging: slot s = c*256 + tid (c in {0,1}), 8 elems.
// row = s>>2, pcg = tid&3, logical cg = (tid&3)^((tid>>3)&3).
#define GEMM_PROLOGUE()                                                    \
  const int srow = tid >> 2;                                               \
  const int scg = (tid & 3) ^ ((tid >> 3) & 3);                            \
  const uint16_t* gA0 = Abase + (size_t)srow * D_ + scg * 8;               \
  const uint16_t* gA1 = gA0 + (size_t)64 * D_;                             \
  const uint16_t* gB0 = Bbase + (size_t)srow * D_ + scg * 8;               \
  const uint16_t* gB1 = gB0 + (size_t)64 * D_;                             \
  uint16_t* lA[2] = {As + tid * 8, As + 4096 + tid * 8};                   \
  uint16_t* lB[2] = {Bs + tid * 8, Bs + 4096 + tid * 8};

#ifdef HAVE_ASYNC_LDS
#define GEMM_STAGE(buf, k)                                                 \
  { g2lds16(gA0 + (k), lA[buf]); g2lds16(gA1 + (k), lA[buf] + 2048);       \
    g2lds16(gB0 + (k), lB[buf]); g2lds16(gB1 + (k), lB[buf] + 2048); }
#else
#define GEMM_STAGE(buf, k)                                                 \
  { *(uint4*)lA[buf] = *(const uint4*)(gA0 + (k));                         \
    *(uint4*)(lA[buf] + 2048) = *(const uint4*)(gA1 + (k));                \
    *(uint4*)lB[buf] = *(const uint4*)(gB0 + (k));                         \
    *(uint4*)(lB[buf] + 2048) = *(const uint4*)(gB1 + (k)); }
#endif

// vmcnt accounting (4 loads/STAGE, per-wave, in-order retirement):
// steady outstanding at wait = 8 (tiles t, t+1); vmcnt(4) retires tile t.
// Last iter (k0=D_-32): only 4 outstanding -> must drain with vmcnt(0).
#define GEMM_KLOOP()                                                       \
  GEMM_PROLOGUE()                                                          \
  GEMM_STAGE(0, 0)                                                         \
  asm volatile("" ::: "memory");                                           \
  GEMM_STAGE(1, 32)                                                        \
  int cur = 0;                                                             \
  for (int k0 = 0; k0 < D_; k0 += 32) {                                    \
    if (k0 + 32 < D_)                                                      \
      asm volatile("s_waitcnt vmcnt(4)\n\ts_barrier" ::: "memory");        \
    else                                                                   \
      asm volatile("s_waitcnt vmcnt(0)\n\ts_barrier" ::: "memory");        \
    const uint16_t* Ac = As + cur * 4096;                                  \
    const uint16_t* Bc = Bs + cur * 4096;                                  \
    bf16x8 af[4], bfr[4];                                                  \
    _Pragma("unroll")                                                      \
    for (int i = 0; i < 4; i++) af[i] = frag32(Ac, wm + i * 16 + r16, quad); \
    _Pragma("unroll")                                                      \
    for (int j = 0; j < 4; j++) bfr[j] = frag32(Bc, wn + j * 16 + r16, quad); \
    asm volatile("s_waitcnt lgkmcnt(0)\n\ts_barrier" ::: "memory");        \
    if (k0 + 64 < D_) { GEMM_STAGE(cur, k0 + 64) }                         \
    _Pragma("unroll")                                                      \
    for (int i = 0; i < 4; i++)                                            \
      _Pragma("unroll")                                                    \
      for (int j = 0; j < 4; j++)                                          \
        acc[i][j] = mfma16(af[i], bfr[j], acc[i][j]);                      \
    cur ^= 1;                                                              \
  }

// ---------------- fused QKV projection + RMSNorm + RoPE -------------------
// Default block mapping: round-robin keeps each XCD on 3 B-panels (n === xcd
// mod 8) -> B L2-resident, A streamed. Measured best (R2/R3 A/B).
__global__ __launch_bounds__(256) void qkv_gemm(
    const uint16_t* __restrict__ Xb, const uint16_t* __restrict__ Wqb,
    const uint16_t* __restrict__ Wkb, const uint16_t* __restrict__ Wvb,
    const float* __restrict__ qnw, const float* __restrict__ knw,
    uint16_t* __restrict__ qbf, uint16_t* __restrict__ kbf,
    uint16_t* __restrict__ vt) {
  __shared__ __align__(16) uint16_t As[2 * BM * 32];
  __shared__ __align__(16) uint16_t Bs[2 * BN * 32];
  const int tid = threadIdx.x;
  const int m0 = blockIdx.y * BM;
  const int n0 = blockIdx.x * BN;

  const uint16_t* Wsrc; int nbase;
  if (n0 < 2048)      { Wsrc = Wqb; nbase = 0; }
  else if (n0 < 2560) { Wsrc = Wkb; nbase = 2048; }
  else                { Wsrc = Wvb; nbase = 2560; }

  const int lane = tid & 63, wave = tid >> 6;
  const int wm = (wave >> 1) * 64, wn = (wave & 1) * 64;
  const int quad = lane >> 4, r16 = lane & 15;
  const uint16_t* Abase = Xb + (size_t)m0 * D_;
  const uint16_t* Bbase = Wsrc + (size_t)(n0 - nbase) * D_;

  floatx4 acc[4][4];
  #pragma unroll
  for (int i = 0; i < 4; i++)
    #pragma unroll
    for (int j = 0; j < 4; j++) acc[i][j] = (floatx4){0.f, 0.f, 0.f, 0.f};

  GEMM_KLOOP()

  if (n0 < 2560) {
    const int isK = (n0 >= 2048);
    const float* nw = isK ? knw : qnw;
    const int head = (n0 - (isK ? 2048 : 0) + wn) >> 6;
    uint16_t* dst = isK ? kbf : qbf;
    const int NH = isK ? HKV_ : H_;
    float wreg[4];
    #pragma unroll
    for (int j = 0; j < 4; j++) wreg[j] = nw[j * 16 + r16];
    float freq[4];
    #pragma unroll
    for (int j = 0; j < 4; j++)
      freq[j] = exp2f((float)(j * 8 + (r16 >> 1)) * -0.0495300781f);  // 3^(-2p/64)
    #pragma unroll
    for (int i = 0; i < 4; i++) {
      #pragma unroll
      for (int r = 0; r < 4; r++) {
        float ss = 0.f;
        #pragma unroll
        for (int j = 0; j < 4; j++) ss += acc[i][j][r] * acc[i][j][r];
        #pragma unroll
        for (int off = 8; off; off >>= 1) ss += __shfl_xor(ss, off);
        float inv = rsqrtf(ss * (1.0f / HD_) + 1e-6f);
        int m = m0 + wm + i * 16 + quad * 4 + r;
        int b = m >> 11, t = m & (T_ - 1);
        size_t rowbase = (((size_t)b * NH + head) * T_ + t) * HD_;
        #pragma unroll
        for (int j = 0; j < 4; j++) {
          float vn = acc[i][j][r] * inv * wreg[j];
          float other = __shfl_xor(vn, 1);
          float f = (float)t * freq[j];
          float s, c;
          __sincosf(f, &s, &c);
          float outv = (r16 & 1) ? (other * s + vn * c) : (vn * c - other * s);
          dst[rowbase + j * 16 + r16] = f2bf(outv);
        }
      }
    }
  } else {
    #pragma unroll
    for (int i = 0; i < 4; i++)
      #pragma unroll
      for (int j = 0; j < 4; j++)
        #pragma unroll
        for (int r = 0; r < 4; r++) {
          int m = m0 + wm + i * 16 + quad * 4 + r;
          int n = n0 + wn + j * 16 + r16 - 2560;
          int b = m >> 11, t = m & (T_ - 1);
          int head = n >> 6, d = n & 63;
          vt[(((size_t)b * HKV_ + head) * HD_ + d) * T_ + t] = f2bf(acc[i][j][r]);
        }
  }
}

// ---------------- O projection GEMM: out = ao @ Wo^T ----------------------
// m-row XCD swizzle (R4-best): 4 A-panels/XCD resident, streams B.
__global__ __launch_bounds__(256) void oproj_gemm(
    const uint16_t* __restrict__ Ab, const uint16_t* __restrict__ Bb,
    float* __restrict__ C) {
  __shared__ __align__(16) uint16_t As[2 * BM * 32];
  __shared__ __align__(16) uint16_t Bs[2 * BN * 32];
  const int tid = threadIdx.x;
  const int lin = (int)blockIdx.y * 16 + (int)blockIdx.x;  // 512 blocks
  const int s = (lin & 7) * 64 + (lin >> 3);               // XCD swizzle
  const int m0 = (s >> 4) * BM;
  const int n0 = (s & 15) * BN;
  const int lane = tid & 63, wave = tid >> 6;
  const int wm = (wave >> 1) * 64, wn = (wave & 1) * 64;
  const int quad = lane >> 4, r16 = lane & 15;
  const uint16_t* Abase = Ab + (size_t)m0 * D_;
  const uint16_t* Bbase = Bb + (size_t)n0 * D_;

  floatx4 acc[4][4];
  #pragma unroll
  for (int i = 0; i < 4; i++)
    #pragma unroll
    for (int j = 0; j < 4; j++) acc[i][j] = (floatx4){0.f, 0.f, 0.f, 0.f};

  GEMM_KLOOP()

  #pragma unroll
  for (int i = 0; i < 4; i++)
    #pragma unroll
    for (int j = 0; j < 4; j++)
      #pragma unroll
      for (int r = 0; r < 4; r++) {
        int m = m0 + wm + i * 16 + quad * 4 + r;
        int n = n0 + wn + j * 16 + r16;
        C[(size_t)m * D_ + n] = acc[i][j][r];
      }
}

// ---------------- Flash attention: S^T + double-buffered staging ----------
// XCD swizzle groups the 16 qt-blocks of each (b,h) on one XCD ->
// that head's K/V (512 KB) stays L2-resident.
// setprio(1) wraps MFMA clusters (T5: attn-positive per m191).
#define LOG2E 1.44269504089f

__global__ __launch_bounds__(256) void attn(const uint16_t* __restrict__ qb,
                                            const uint16_t* __restrict__ kb,
                                            const uint16_t* __restrict__ vtb,
                                            uint16_t* __restrict__ ao) {
  const int tid = threadIdx.x;
  const int wave = tid >> 6, lane = tid & 63;
  const int quad = lane >> 4, r16 = lane & 15;
  const int lin = ((int)blockIdx.z * 32 + (int)blockIdx.y) * 16 + (int)blockIdx.x;
  const int s = (lin & 7) * 128 + (lin >> 3);  // XCD swizzle (1024 blocks)
  const int bx = s & 15;
  const int h  = (s >> 4) & 31;
  const int b  = s >> 9;
  const int kvh = h >> 2;

  const uint16_t* Q  = qb  + ((size_t)b * H_ + h) * T_ * HD_;
  const uint16_t* K  = kb  + ((size_t)b * HKV_ + kvh) * T_ * HD_;
  const uint16_t* Vt = vtb + ((size_t)b * HKV_ + kvh) * (size_t)HD_ * T_;

  __shared__ __align__(16) uint16_t Kl[2][64 * 64];
  __shared__ __align__(16) uint16_t Vl[2][64 * 64];

  // staging constants (K: pcg=cg^(row&7); V: pcg=cg^((row>>1)&7))
  const int l3 = lane >> 3, l7 = lane & 7, l4 = lane >> 4;
  const int cgK  = l7 ^ l3;
  const int cgV0 = l7 ^ (l4 & 7);
  const int cgV1 = l7 ^ ((4 + l4) & 7);
  const int sOff = wave * 16 * 64 + lane * 8;  // dst for row block 0; +512 for block 1

  // fragment read offsets (elements), loop-invariant
  const int koffE0 = r16 * 64 + ((quad)     ^ (r16 & 7)) * 8;
  const int koffE1 = r16 * 64 + ((4 + quad) ^ (r16 & 7)) * 8;
  int voffE[4];
  #pragma unroll
  for (int mt = 0; mt < 4; mt++)
    voffE[mt] = r16 * 64 + (((mt * 2 + (quad >> 1)) ^ ((r16 >> 1) & 7)) * 8) + (quad & 1) * 4;
  float dm[4];
  #pragma unroll
  for (int r = 0; r < 4; r++) dm[r] = (quad * 4 + r <= r16) ? 1.0f : 0.0f;

#ifdef HAVE_ASYNC_LDS
#define AT_STAGE(buf)                                                     \
  { g2lds16(kg0, &Kl[buf][sOff]); g2lds16(kg1, &Kl[buf][sOff + 512]);     \
    g2lds16(vg0, &Vl[buf][sOff]); g2lds16(vg1, &Vl[buf][sOff + 512]);     \
    kg0 += 64 * HD_; kg1 += 64 * HD_; vg0 += 64; vg1 += 64; }
#else
#define AT_STAGE(buf)                                                     \
  { *(uint4*)&Kl[buf][sOff] = *(const uint4*)kg0;                         \
    *(uint4*)&Kl[buf][sOff + 512] = *(const uint4*)kg1;                   \
    *(uint4*)&Vl[buf][sOff] = *(const uint4*)vg0;                         \
    *(uint4*)&Vl[buf][sOff + 512] = *(const uint4*)vg1;                   \
    kg0 += 64 * HD_; kg1 += 64 * HD_; vg0 += 64; vg1 += 64; }
#endif

#define AT_CHUNK(mt, MASKED)                                              \
  {                                                                       \
    bf16x8 kf0 = *(const bf16x8*)&Kc[koffE0 + (mt) * 1024];               \
    bf16x8 kf1 = *(const bf16x8*)&Kc[koffE1 + (mt) * 1024];               \
    floatx4 st = (floatx4){0.f, 0.f, 0.f, 0.f};                           \
    __builtin_amdgcn_s_setprio(1);                                        \
    st = mfma16(kf0, bq[0], st);                                          \
    st = mfma16(kf1, bq[1], st);                                          \
    __builtin_amdgcn_s_setprio(0);                                        \
    float pv[4];                                                          \
    _Pragma("unroll")                                                     \
    for (int r = 0; r < 4; r++) {                                         \
      pv[r] = fast_exp2(fmaf(st[r], SCALE_ * LOG2E, -8.0f * LOG2E));      \
      if (MASKED) pv[r] *= dm[r];                                         \
      l += pv[r];                                                         \
    }                                                                     \
    uint64_t pu = (uint64_t)pack_p(pv[0], pv[1]) |                        \
                  ((uint64_t)pack_p(pv[2], pv[3]) << 32);                 \
    bf16x4 pa = __builtin_bit_cast(bf16x4, pu);                           \
    __builtin_amdgcn_s_setprio(1);                                        \
    _Pragma("unroll")                                                     \
    for (int jn = 0; jn < 4; jn++) {                                      \
      bf16x4 vf = *(const bf16x4*)&Vc[voffE[mt] + jn * 1024];             \
      o[jn] = mfma16k16(pa, vf, o[jn]);                                   \
    }                                                                     \
    __builtin_amdgcn_s_setprio(0);                                        \
  }

  for (int pass = 0; pass < 2; pass++) {
    const int qt = pass ? bx : 31 - bx;
    const int q0 = qt * 64;
    const int Rw = q0 + wave * 16;

    bf16x8 bq[2];
    #pragma unroll
    for (int hh = 0; hh < 2; hh++)
      bq[hh] = *(const bf16x8*)(Q + (size_t)(Rw + r16) * HD_ + hh * 32 + quad * 8);

    floatx4 o[4];
    float l = 0.f;
    #pragma unroll
    for (int jn = 0; jn < 4; jn++) o[jn] = (floatx4){0.f, 0.f, 0.f, 0.f};

    const uint16_t* kg0 = K + (size_t)(wave * 16 + l3) * HD_ + cgK * 8;
    const uint16_t* kg1 = K + (size_t)(wave * 16 + 8 + l3) * HD_ + cgK * 8;
    const uint16_t* vg0 = Vt + (size_t)(wave * 16 + l3) * T_ + cgV0 * 8;
    const uint16_t* vg1 = Vt + (size_t)(wave * 16 + 8 + l3) * T_ + cgV1 * 8;

    __syncthreads();  // all readers of both buffers (prev pass) done
    AT_STAGE(0)
    int cur = 0;

    // full iterations (mask-free for every wave), prefetching it+1
    for (int it = 0; it < qt; it++) {
      __syncthreads();          // publishes buf[cur]; drains this wave's stage ops
      AT_STAGE(cur ^ 1)         // prefetch it+1 (always valid: it+1 <= qt)
      const uint16_t* Kc = Kl[cur];
      const uint16_t* Vc = Vl[cur];
      AT_CHUNK(0, false)
      AT_CHUNK(1, false)
      AT_CHUNK(2, false)
      AT_CHUNK(3, false)
      cur ^= 1;
    }
    // diagonal iteration (kt = q0)
    __syncthreads();
    {
      const uint16_t* Kc = Kl[cur];
      const uint16_t* Vc = Vl[cur];
      #pragma unroll
      for (int mt = 0; mt < 4; mt++) {
        if (mt < wave) AT_CHUNK(mt, false)
        else if (mt == wave) AT_CHUNK(mt, true)
      }
    }

    // l: reduce over quads, transpose to rows, normalize, store
    l += __shfl_xor(l, 16);
    l += __shfl_xor(l, 32);
    float lq[4];
    #pragma unroll
    for (int r = 0; r < 4; r++) lq[r] = __shfl(l, quad * 4 + r);

    #pragma unroll
    for (int jn = 0; jn < 4; jn++) {
      uint32_t u01 = f2bf_pk(o[jn][0] / lq[0], o[jn][1] / lq[1]);
      uint32_t u23 = f2bf_pk(o[jn][2] / lq[2], o[jn][3] / lq[3]);
      int t0 = Rw + quad * 4;
      size_t base = ((size_t)b * T_ + t0) * (H_ * HD_) + h * HD_ + jn * 16 + r16;
      ao[base]                = (uint16_t)u01;
      ao[base + 1 * H_ * HD_] = (uint16_t)(u01 >> 16);
      ao[base + 2 * H_ * HD_] = (uint16_t)u23;
      ao[base + 3 * H_ * HD_] = (uint16_t)(u23 >> 16);
    }
  }
#undef AT_STAGE
#undef AT_CHUNK
}

extern "C" void kernel_launch(void* const* d_in, const int* in_sizes, int n_in,
                              void* d_out, int out_size, void* d_ws, size_t ws_size,
                              hipStream_t stream) {
  const float* x  = (const float*)d_in[0];
  const float* Wq = (const float*)d_in[1];
  const float* Wk = (const float*)d_in[2];
  const float* Wv = (const float*)d_in[3];
  const float* Wo = (const float*)d_in[4];
  const float* qw = (const float*)d_in[5];
  const float* kw = (const float*)d_in[6];
  float* out = (float*)d_out;

  char* ws = (char*)d_ws;
  uint16_t* xb  = (uint16_t*)(ws);               // 16 MB  x bf16 (later: ao bf16)
  uint16_t* wqb = (uint16_t*)(ws + 16777216);    // 8 MB
  uint16_t* wkb = (uint16_t*)(ws + 25165824);    // 2 MB
  uint16_t* wvb = (uint16_t*)(ws + 27262976);    // 2 MB
  uint16_t* wob = (uint16_t*)(ws + 29360128);    // 8 MB
  uint16_t* qbf = (uint16_t*)(ws + 37748736);    // 16 MB  q bf16 (b,h,t,d) post norm+rope
  uint16_t* kbf = (uint16_t*)(ws + 54525952);    // 4 MB   k bf16 (b,kvh,t,d)
  uint16_t* vtb = (uint16_t*)(ws + 58720256);    // 4 MB   V^T bf16 (b,kvh,d,t)
  uint16_t* aob = xb;

  cvt_all<<<18432, 256, 0, stream>>>(x, Wq, Wk, Wv, Wo, xb, wqb, wkb, wvb, wob);

  qkv_gemm<<<dim3(24, 32), 256, 0, stream>>>(xb, wqb, wkb, wvb, qw, kw, qbf, kbf, vtb);

  attn<<<dim3(16, 32, 2), 256, 0, stream>>>(qbf, kbf, vtb, aob);

  oproj_gemm<<<dim3(16, 32), 256, 0, stream>>>(aob, wob, out);
}